// Round 1
// baseline (1477.130 us; speedup 1.0000x reference)
//
#include <hip/hip_runtime.h>
#include <float.h>
#include <math.h>

#define HH 40
#define WW 128
#define PP 5120
#define NN 5120
#define CC 128
#define KK 25
#define SPOT 5
#define NEGV -1e8f

#define TM 64
#define TN 64
#define CSPLIT 4

// ---------------- K1: L2-normalize rows (fp64 norm, fp32 stored) ----------------
__global__ void k_normalize(const float* __restrict__ imf, const float* __restrict__ pcf,
                            float* __restrict__ imn, float* __restrict__ pcn) {
    int row = blockIdx.x * 4 + (threadIdx.x >> 6);
    int lane = threadIdx.x & 63;
    const float* src; float* dst; int r;
    if (row < PP) { src = imf; dst = imn; r = row; }
    else          { src = pcf; dst = pcn; r = row - PP; }
    float2 v = *(const float2*)&src[r * CC + lane * 2];
    double ss = (double)v.x * (double)v.x + (double)v.y * (double)v.y;
#pragma unroll
    for (int o = 32; o; o >>= 1) ss += __shfl_xor(ss, o);
    double inv = 1.0 / fmax(sqrt(ss), 1e-12);
    float2 o2 = make_float2((float)((double)v.x * inv), (float)((double)v.y * inv));
    *(float2*)&dst[r * CC + lane * 2] = o2;
}

// ---------------- K2: KNN top-25 (ascending d2, self first, low-index ties) ------
__global__ void k_knn(const float* __restrict__ pts, int* __restrict__ nb) {
    __shared__ double d2[NN];
    __shared__ double rv[4];
    __shared__ int    ri[4];
    int i = blockIdx.x;
    int t = threadIdx.x;
    double px = pts[i * 3 + 0], py = pts[i * 3 + 1], pz = pts[i * 3 + 2];
    for (int j = t; j < NN; j += 256) {
        double dx = px - (double)pts[j * 3 + 0];
        double dy = py - (double)pts[j * 3 + 1];
        double dz = pz - (double)pts[j * 3 + 2];
        d2[j] = dx * dx + dy * dy + dz * dz;
    }
    __syncthreads();
    for (int it = 0; it < KK; ++it) {
        double bv = DBL_MAX; int bi = NN;
        for (int j = t; j < NN; j += 256) {
            double v = d2[j];
            if (v < bv || (v == bv && j < bi)) { bv = v; bi = j; }
        }
#pragma unroll
        for (int o = 32; o; o >>= 1) {
            double ov = __shfl_xor(bv, o); int oi = __shfl_xor(bi, o);
            if (ov < bv || (ov == bv && oi < bi)) { bv = ov; bi = oi; }
        }
        if ((t & 63) == 0) { rv[t >> 6] = bv; ri[t >> 6] = bi; }
        __syncthreads();
        if (t == 0) {
            for (int wv = 1; wv < 4; ++wv)
                if (rv[wv] < bv || (rv[wv] == bv && ri[wv] < bi)) { bv = rv[wv]; bi = ri[wv]; }
            nb[i * KK + it] = bi;
            d2[bi] = DBL_MAX;
        }
        __syncthreads();
    }
}

// ---------------- K3: tiled cosine row-max/argmax (fp64 accumulate) --------------
__global__ __launch_bounds__(256, 2) void k_rowmax(const float* __restrict__ A,
                                                   const float* __restrict__ B,
                                                   int nB,
                                                   double* __restrict__ pval,
                                                   int* __restrict__ pidx,
                                                   int nA) {
    __shared__ float As[CC * TM];
    __shared__ float Bs[CC * TN];
    __shared__ double sred[TM * 16];
    __shared__ int    sredi[TM * 16];

    int t = threadIdx.x;
    int rb = blockIdx.x * TM;
    int segLen = nB / CSPLIT;
    int segBase = blockIdx.y * segLen;

    // stage A tile transposed: As[c][r]
    for (int q = t; q < TM * CC / 4; q += 256) {
        int row = q >> 5;      // CC/4 = 32 float4 per row
        int c4 = q & 31;
        float4 v = *(const float4*)&A[(rb + row) * CC + c4 * 4];
        int c = c4 << 2;
        As[(c + 0) * TM + row] = v.x;
        As[(c + 1) * TM + row] = v.y;
        As[(c + 2) * TM + row] = v.z;
        As[(c + 3) * TM + row] = v.w;
    }

    int ty = t >> 4, tx = t & 15;
    double bv[4] = {-1e300, -1e300, -1e300, -1e300};
    int    bi[4] = {0, 0, 0, 0};

    for (int ch = 0; ch < segLen; ch += TN) {
        __syncthreads();
        for (int q = t; q < TN * CC / 4; q += 256) {
            int row = q >> 5;
            int c4 = q & 31;
            float4 v = *(const float4*)&B[(segBase + ch + row) * CC + c4 * 4];
            int c = c4 << 2;
            Bs[(c + 0) * TN + row] = v.x;
            Bs[(c + 1) * TN + row] = v.y;
            Bs[(c + 2) * TN + row] = v.z;
            Bs[(c + 3) * TN + row] = v.w;
        }
        __syncthreads();

        double acc[4][4];
#pragma unroll
        for (int ii = 0; ii < 4; ++ii)
#pragma unroll
            for (int jj = 0; jj < 4; ++jj) acc[ii][jj] = 0.0;

#pragma unroll 4
        for (int c = 0; c < CC; ++c) {
            float4 af = *(const float4*)&As[c * TM + ty * 4];
            float4 bf = *(const float4*)&Bs[c * TN + tx * 4];
            double a0 = af.x, a1 = af.y, a2 = af.z, a3 = af.w;
            double b0 = bf.x, b1 = bf.y, b2 = bf.z, b3 = bf.w;
            acc[0][0] += a0 * b0; acc[0][1] += a0 * b1; acc[0][2] += a0 * b2; acc[0][3] += a0 * b3;
            acc[1][0] += a1 * b0; acc[1][1] += a1 * b1; acc[1][2] += a1 * b2; acc[1][3] += a1 * b3;
            acc[2][0] += a2 * b0; acc[2][1] += a2 * b1; acc[2][2] += a2 * b2; acc[2][3] += a2 * b3;
            acc[3][0] += a3 * b0; acc[3][1] += a3 * b1; acc[3][2] += a3 * b2; acc[3][3] += a3 * b3;
        }

        int cb = segBase + ch + tx * 4;
#pragma unroll
        for (int ii = 0; ii < 4; ++ii)
#pragma unroll
            for (int jj = 0; jj < 4; ++jj) {
                double v = acc[ii][jj];
                int cj = cb + jj;
                if (v > bv[ii] || (v == bv[ii] && cj < bi[ii])) { bv[ii] = v; bi[ii] = cj; }
            }
    }

    __syncthreads();
#pragma unroll
    for (int ii = 0; ii < 4; ++ii) {
        sred[(ty * 4 + ii) * 16 + tx]  = bv[ii];
        sredi[(ty * 4 + ii) * 16 + tx] = bi[ii];
    }
    __syncthreads();
    if (t < TM) {
        double v = sred[t * 16]; int ix = sredi[t * 16];
        for (int x = 1; x < 16; ++x) {
            double vv = sred[t * 16 + x]; int ii = sredi[t * 16 + x];
            if (vv > v || (vv == v && ii < ix)) { v = vv; ix = ii; }
        }
        pval[blockIdx.y * nA + rb + t] = v;
        pidx[blockIdx.y * nA + rb + t] = ix;
    }
}

// ---------------- K3b: reduce column-split partials ------------------------------
__global__ void k_reduce_best(const double* __restrict__ pvalA, const int* __restrict__ pidxA,
                              const double* __restrict__ pvalB, const int* __restrict__ pidxB,
                              double* __restrict__ bestSd, int* __restrict__ bestI,
                              double* __restrict__ bestPSd, int* __restrict__ bestPI) {
    int r = blockIdx.x * 256 + threadIdx.x;
    if (r >= PP) return;
    {
        double v = pvalA[r]; int ix = pidxA[r];
        for (int s = 1; s < CSPLIT; ++s) {
            double vv = pvalA[s * PP + r]; int ii = pidxA[s * PP + r];
            if (vv > v || (vv == v && ii < ix)) { v = vv; ix = ii; }
        }
        bestSd[r] = v; bestI[r] = ix;
    }
    {
        double v = pvalB[r]; int ix = pidxB[r];
        for (int s = 1; s < CSPLIT; ++s) {
            double vv = pvalB[s * NN + r]; int ii = pidxB[s * NN + r];
            if (vv > v || (vv == v && ii < ix)) { v = vv; ix = ii; }
        }
        bestPSd[r] = v; bestPI[r] = ix;
    }
}

// ---------------- K4: image sim/softmax + select output + seeding ----------------
__global__ void k_im_select(const float* __restrict__ imn,
                            const double* __restrict__ bestSd,
                            const int* __restrict__ bestI,
                            float* __restrict__ outSelect,
                            int* __restrict__ seed) {
    int p = blockIdx.x * 4 + (threadIdx.x >> 6);
    int lane = threadIdx.x & 63;
    int h = p >> 7;       // /W, W=128
    int w = p & 127;
    float2 ctr = *(const float2*)&imn[p * CC + lane * 2];

    double sim[KK];
#pragma unroll
    for (int k = 0; k < KK; ++k) {
        int di = k / 5 - 2, dj = k % 5 - 2;
        int hc = min(max(h + di, 0), HH - 1);
        int wc = min(max(w + dj, 0), WW - 1);
        int q = hc * WW + wc;
        float2 nv = *(const float2*)&imn[q * CC + lane * 2];
        double part = (double)ctr.x * (double)nv.x + (double)ctr.y * (double)nv.y;
#pragma unroll
        for (int o = 32; o; o >>= 1) part += __shfl_xor(part, o);
        sim[k] = part;
    }
    double mx = sim[0];
#pragma unroll
    for (int k = 1; k < KK; ++k) mx = fmax(mx, sim[k]);
    double sum = 0.0;
#pragma unroll
    for (int k = 0; k < KK; ++k) { sim[k] = exp(sim[k] - mx); sum += sim[k]; }
    double inv = 1.0 / sum;

    double sel[KK];
#pragma unroll
    for (int k = 0; k < KK; ++k) {
        int di = k / 5 - 2, dj = k % 5 - 2;
        int h2 = h + di, w2 = w + dj;
        bool valid = (h2 >= 0 && h2 < HH && w2 >= 0 && w2 < WW);
        int hc = min(max(h2, 0), HH - 1), wc = min(max(w2, 0), WW - 1);
        double conf = bestSd[hc * WW + wc];
        double so = valid ? (sim[k] * inv * conf) : (double)NEGV;
        if (lane == k) outSelect[k * PP + p] = (float)so;
        sel[k] = (k == 12) ? (double)NEGV : so;
    }

    // top-4 (ascending-k strict > == lax.top_k low-index tie-break)
    int tk1 = 0, tk2 = 0, tk3 = 0, tk4 = 0;
    {
        unsigned chosen = 1u << 12;
#pragma unroll
        for (int s = 0; s < 4; ++s) {
            double bvv = -1e300; int bk = 0;
#pragma unroll
            for (int k = 0; k < KK; ++k)
                if (!((chosen >> k) & 1) && sel[k] > bvv) { bvv = sel[k]; bk = k; }
            chosen |= 1u << bk;
            if (s == 0) tk1 = bk; else if (s == 1) tk2 = bk; else if (s == 2) tk3 = bk; else tk4 = bk;
        }
    }
    if (lane == 0) {
        int tks[5] = {12, tk1, tk2, tk3, tk4};
#pragma unroll
        for (int s = 0; s < 5; ++s) {
            int k = tks[s];
            int di = k / 5 - 2, dj = k % 5 - 2;
            int h2 = h + di, w2 = w + dj;
            int pix = (h2 >= 0 && h2 < HH && w2 >= 0 && w2 < WW) ? (h2 * WW + w2) : -1;
            pix = min(max(pix, 0), PP - 1);
            seed[p * SPOT + s] = bestI[pix];
        }
    }
}

// ---------------- K6: pc sim/softmax + seeding -----------------------------------
__global__ void k_pc_select(const float* __restrict__ pcn,
                            const int* __restrict__ nb,
                            const double* __restrict__ bestPSd,
                            const int* __restrict__ bestPI,
                            int* __restrict__ pcseed) {
    int i = blockIdx.x * 4 + (threadIdx.x >> 6);
    int lane = threadIdx.x & 63;
    float2 ctr = *(const float2*)&pcn[i * CC + lane * 2];

    int nbr[KK];
#pragma unroll
    for (int k = 0; k < KK; ++k) nbr[k] = nb[i * KK + k];

    double sim[KK];
#pragma unroll
    for (int k = 0; k < KK; ++k) {
        float2 nv = *(const float2*)&pcn[nbr[k] * CC + lane * 2];
        double part = (double)ctr.x * (double)nv.x + (double)ctr.y * (double)nv.y;
#pragma unroll
        for (int o = 32; o; o >>= 1) part += __shfl_xor(part, o);
        sim[k] = part;
    }
    double mx = sim[0];
#pragma unroll
    for (int k = 1; k < KK; ++k) mx = fmax(mx, sim[k]);
    double sum = 0.0;
#pragma unroll
    for (int k = 0; k < KK; ++k) { sim[k] = exp(sim[k] - mx); sum += sim[k]; }
    double inv = 1.0 / sum;

    double sel[KK];
    sel[0] = (double)NEGV;
#pragma unroll
    for (int k = 1; k < KK; ++k) sel[k] = sim[k] * inv * bestPSd[nbr[k]];

    int tk1 = 0, tk2 = 0, tk3 = 0, tk4 = 0;
    {
        unsigned chosen = 0u;
#pragma unroll
        for (int s = 0; s < 4; ++s) {
            double bvv = -1e300; int bk = 0;
#pragma unroll
            for (int k = 0; k < KK; ++k)
                if (!((chosen >> k) & 1) && sel[k] > bvv) { bvv = sel[k]; bk = k; }
            chosen |= 1u << bk;
            if (s == 0) tk1 = bk; else if (s == 1) tk2 = bk; else if (s == 2) tk3 = bk; else tk4 = bk;
        }
    }
    if (lane == 0) {
        int tks[5] = {0, tk1, tk2, tk3, tk4};
#pragma unroll
        for (int s = 0; s < 5; ++s)
            pcseed[i * SPOT + s] = bestPI[nbr[tks[s]]];
    }
}

// ---------------- bitmap -> stable top-125 compaction ----------------------------
__device__ __forceinline__ void compact_bits(const unsigned* bits, int row,
                                             float* __restrict__ maskOut,
                                             float* __restrict__ idxOut, int lane) {
    int base = 0;
    for (int w = 0; w < 160 && base < 125; ++w) {
        unsigned word = bits[w];
        int cnt = __popc(word);
        if (lane < cnt) {
            unsigned v = word;
            for (int t = 0; t < lane; ++t) v &= v - 1;
            int pos = __ffs((int)v) - 1;
            idxOut[row * 125 + base + lane]  = (float)(w * 32 + pos);
            maskOut[row * 125 + base + lane] = 1.0f;
        }
        base += cnt;
    }
    for (int w = 0; w < 160 && base < 125; ++w) {
        unsigned word = ~bits[w];
        int cnt = __popc(word);
        int take = min(cnt, 125 - base);
        if (lane < take) {
            unsigned v = word;
            for (int t = 0; t < lane; ++t) v &= v - 1;
            int pos = __ffs((int)v) - 1;
            idxOut[row * 125 + base + lane]  = (float)(w * 32 + pos);
            maskOut[row * 125 + base + lane] = 0.0f;
        }
        base += take;
    }
}

// ---------------- K5: im spoting ------------------------------------------------
__global__ void k_im_spot(const int* __restrict__ seed, const int* __restrict__ nb,
                          float* __restrict__ maskOut, float* __restrict__ idxOut) {
    __shared__ unsigned bits[4][160];
    int wid = threadIdx.x >> 6, lane = threadIdx.x & 63;
    int p = blockIdx.x * 4 + wid;
    for (int w = lane; w < 160; w += 64) bits[wid][w] = 0u;
    __syncthreads();
    for (int e = lane; e < 125; e += 64) {
        int sd = seed[p * SPOT + e / 25];
        int pt = nb[sd * KK + (e % 25)];
        atomicOr(&bits[wid][pt >> 5], 1u << (pt & 31));
    }
    __syncthreads();
    compact_bits(bits[wid], p, maskOut, idxOut, lane);
}

// ---------------- K7: pc spoting ------------------------------------------------
__global__ void k_pc_spot(const int* __restrict__ pcseed,
                          float* __restrict__ maskOut, float* __restrict__ idxOut) {
    __shared__ unsigned bits[4][160];
    int wid = threadIdx.x >> 6, lane = threadIdx.x & 63;
    int i = blockIdx.x * 4 + wid;
    for (int w = lane; w < 160; w += 64) bits[wid][w] = 0u;
    __syncthreads();
    for (int e = lane; e < 125; e += 64) {
        int q = pcseed[i * SPOT + e / 25];
        int kk = e % 25;
        int r0 = q >> 7, c0 = q & 127;
        int r = min(max(r0 + kk / 5 - 2, 0), HH - 1);
        int c = min(max(c0 + kk % 5 - 2, 0), WW - 1);
        int pix = r * WW + c;
        atomicOr(&bits[wid][pix >> 5], 1u << (pix & 31));
    }
    __syncthreads();
    compact_bits(bits[wid], i, maskOut, idxOut, lane);
}

// ---------------- host ----------------------------------------------------------
extern "C" void kernel_launch(void* const* d_in, const int* in_sizes, int n_in,
                              void* d_out, int out_size, void* d_ws, size_t ws_size,
                              hipStream_t stream) {
    const float* imf = (const float*)d_in[0];
    const float* pcf = (const float*)d_in[1];
    const float* pts = (const float*)d_in[2];
    float* out = (float*)d_out;

    char* w = (char*)d_ws;
    double* bestSd  = (double*)w;  w += (size_t)PP * 8;
    double* bestPSd = (double*)w;  w += (size_t)NN * 8;
    double* pvalA   = (double*)w;  w += (size_t)CSPLIT * PP * 8;
    double* pvalB   = (double*)w;  w += (size_t)CSPLIT * NN * 8;
    float*  imn     = (float*)w;   w += (size_t)PP * CC * 4;
    float*  pcn     = (float*)w;   w += (size_t)NN * CC * 4;
    int*    nb      = (int*)w;     w += (size_t)NN * KK * 4;
    int*    bestI   = (int*)w;     w += (size_t)PP * 4;
    int*    bestPI  = (int*)w;     w += (size_t)NN * 4;
    int*    pidxA   = (int*)w;     w += (size_t)CSPLIT * PP * 4;
    int*    pidxB   = (int*)w;     w += (size_t)CSPLIT * NN * 4;
    int*    seed    = (int*)w;     w += (size_t)PP * SPOT * 4;
    int*    pcseed  = (int*)w;     w += (size_t)NN * SPOT * 4;

    float* outSelect = out;                       // (25, 5120)
    float* outMask   = out + KK * PP;             // (5120, 125)
    float* outIdx    = outMask + PP * 125;        // (5120, 125)
    float* outIdxPc  = outIdx + PP * 125;         // (5120, 125)
    float* outMaskPc = outIdxPc + NN * 125;       // (5120, 125)

    k_normalize<<<(PP + NN) / 4, 256, 0, stream>>>(imf, pcf, imn, pcn);
    k_knn<<<NN, 256, 0, stream>>>(pts, nb);
    k_rowmax<<<dim3(PP / TM, CSPLIT), 256, 0, stream>>>(imn, pcn, NN, pvalA, pidxA, PP);
    k_rowmax<<<dim3(NN / TM, CSPLIT), 256, 0, stream>>>(pcn, imn, PP, pvalB, pidxB, NN);
    k_reduce_best<<<PP / 256, 256, 0, stream>>>(pvalA, pidxA, pvalB, pidxB,
                                                bestSd, bestI, bestPSd, bestPI);
    k_im_select<<<PP / 4, 256, 0, stream>>>(imn, bestSd, bestI, outSelect, seed);
    k_pc_select<<<NN / 4, 256, 0, stream>>>(pcn, nb, bestPSd, bestPI, pcseed);
    k_im_spot<<<PP / 4, 256, 0, stream>>>(seed, nb, outMask, outIdx);
    k_pc_spot<<<NN / 4, 256, 0, stream>>>(pcseed, outMaskPc, outIdxPc);
}

// Round 2
// 834.169 us; speedup vs baseline: 1.7708x; 1.7708x over previous
//
#include <hip/hip_runtime.h>
#include <float.h>
#include <math.h>

#define HH 40
#define WW 128
#define PP 5120
#define NN 5120
#define CC 128
#define KK 25
#define SPOT 5
#define NEGV -1e8f

#define TM 64
#define TN 64
#define CSPLIT 16

// ---------------- K1: L2-normalize rows (fp64 norm, fp32 stored) ----------------
__global__ void k_normalize(const float* __restrict__ imf, const float* __restrict__ pcf,
                            float* __restrict__ imn, float* __restrict__ pcn) {
    int row = blockIdx.x * 4 + (threadIdx.x >> 6);
    int lane = threadIdx.x & 63;
    const float* src; float* dst; int r;
    if (row < PP) { src = imf; dst = imn; r = row; }
    else          { src = pcf; dst = pcn; r = row - PP; }
    float2 v = *(const float2*)&src[r * CC + lane * 2];
    double ss = (double)v.x * (double)v.x + (double)v.y * (double)v.y;
#pragma unroll
    for (int o = 32; o; o >>= 1) ss += __shfl_xor(ss, o);
    double inv = 1.0 / fmax(sqrt(ss), 1e-12);
    float2 o2 = make_float2((float)((double)v.x * inv), (float)((double)v.y * inv));
    *(float2*)&dst[r * CC + lane * 2] = o2;
}

// ---------------- K2: KNN top-25, register-tournament version --------------------
// Each thread owns 20 d2 values in registers (static indexing only; removal via
// bitmask, NOT runtime-indexed stores, which would spill the array to scratch).
__global__ __launch_bounds__(256) void k_knn(const float* __restrict__ pts,
                                             int* __restrict__ nb) {
    __shared__ double sv[2][4];
    __shared__ int    si[2][4];
    int i = blockIdx.x;
    int t = threadIdx.x;
    int wid = t >> 6, lane = t & 63;
    double px = pts[i * 3 + 0], py = pts[i * 3 + 1], pz = pts[i * 3 + 2];

    double d[20];
    int base = t * 20;
    double lv = DBL_MAX; int li = 0x7fffffff;
#pragma unroll
    for (int e = 0; e < 20; ++e) {
        int j = base + e;
        double dx = px - (double)pts[j * 3 + 0];
        double dy = py - (double)pts[j * 3 + 1];
        double dz = pz - (double)pts[j * 3 + 2];
        double v = dx * dx + dy * dy + dz * dz;
        d[e] = v;
        if (v < lv) { lv = v; li = j; }   // ascending e => low-index tie-break
    }

    unsigned removed = 0u;
    for (int it = 0; it < KK; ++it) {
        double bv = lv; int bi = li;
#pragma unroll
        for (int o = 32; o; o >>= 1) {
            double ov = __shfl_xor(bv, o); int oi = __shfl_xor(bi, o);
            if (ov < bv || (ov == bv && oi < bi)) { bv = ov; bi = oi; }
        }
        int par = it & 1;
        if (lane == 0) { sv[par][wid] = bv; si[par][wid] = bi; }
        __syncthreads();
        bv = sv[par][0]; bi = si[par][0];
#pragma unroll
        for (int wv = 1; wv < 4; ++wv) {
            double ov = sv[par][wv]; int oi = si[par][wv];
            if (ov < bv || (ov == bv && oi < bi)) { bv = ov; bi = oi; }
        }
        if (t == 0) nb[i * KK + it] = bi;
        if (bi >= base && bi < base + 20) {
            removed |= 1u << (bi - base);
            lv = DBL_MAX; li = 0x7fffffff;
#pragma unroll
            for (int e = 0; e < 20; ++e) {
                bool alive = !((removed >> e) & 1u);
                if (alive && d[e] < lv) { lv = d[e]; li = base + e; }
            }
        }
        // single barrier per iter is safe: next iter writes the other parity
        // slot, and nobody re-writes this parity until after the next barrier.
    }
}

// ---------------- K3: tiled cosine row-max/argmax (fp64 accumulate) --------------
__global__ __launch_bounds__(256, 2) void k_rowmax(const float* __restrict__ A,
                                                   const float* __restrict__ B,
                                                   int nB,
                                                   double* __restrict__ pval,
                                                   int* __restrict__ pidx,
                                                   int nA) {
    __shared__ float As[CC * TM];
    __shared__ float Bs[CC * TN];
    __shared__ double sred[TM * 16];
    __shared__ int    sredi[TM * 16];

    int t = threadIdx.x;
    int rb = blockIdx.x * TM;
    int segLen = nB / CSPLIT;
    int segBase = blockIdx.y * segLen;

    // stage A tile transposed: As[c][r]
    for (int q = t; q < TM * CC / 4; q += 256) {
        int row = q >> 5;      // CC/4 = 32 float4 per row
        int c4 = q & 31;
        float4 v = *(const float4*)&A[(rb + row) * CC + c4 * 4];
        int c = c4 << 2;
        As[(c + 0) * TM + row] = v.x;
        As[(c + 1) * TM + row] = v.y;
        As[(c + 2) * TM + row] = v.z;
        As[(c + 3) * TM + row] = v.w;
    }

    int ty = t >> 4, tx = t & 15;
    double bv[4] = {-1e300, -1e300, -1e300, -1e300};
    int    bi[4] = {0, 0, 0, 0};

    for (int ch = 0; ch < segLen; ch += TN) {
        __syncthreads();
        for (int q = t; q < TN * CC / 4; q += 256) {
            int row = q >> 5;
            int c4 = q & 31;
            float4 v = *(const float4*)&B[(segBase + ch + row) * CC + c4 * 4];
            int c = c4 << 2;
            Bs[(c + 0) * TN + row] = v.x;
            Bs[(c + 1) * TN + row] = v.y;
            Bs[(c + 2) * TN + row] = v.z;
            Bs[(c + 3) * TN + row] = v.w;
        }
        __syncthreads();

        double acc[4][4];
#pragma unroll
        for (int ii = 0; ii < 4; ++ii)
#pragma unroll
            for (int jj = 0; jj < 4; ++jj) acc[ii][jj] = 0.0;

#pragma unroll 4
        for (int c = 0; c < CC; ++c) {
            float4 af = *(const float4*)&As[c * TM + ty * 4];
            float4 bf = *(const float4*)&Bs[c * TN + tx * 4];
            double a0 = af.x, a1 = af.y, a2 = af.z, a3 = af.w;
            double b0 = bf.x, b1 = bf.y, b2 = bf.z, b3 = bf.w;
            acc[0][0] += a0 * b0; acc[0][1] += a0 * b1; acc[0][2] += a0 * b2; acc[0][3] += a0 * b3;
            acc[1][0] += a1 * b0; acc[1][1] += a1 * b1; acc[1][2] += a1 * b2; acc[1][3] += a1 * b3;
            acc[2][0] += a2 * b0; acc[2][1] += a2 * b1; acc[2][2] += a2 * b2; acc[2][3] += a2 * b3;
            acc[3][0] += a3 * b0; acc[3][1] += a3 * b1; acc[3][2] += a3 * b2; acc[3][3] += a3 * b3;
        }

        int cb = segBase + ch + tx * 4;
#pragma unroll
        for (int ii = 0; ii < 4; ++ii)
#pragma unroll
            for (int jj = 0; jj < 4; ++jj) {
                double v = acc[ii][jj];
                int cj = cb + jj;
                if (v > bv[ii] || (v == bv[ii] && cj < bi[ii])) { bv[ii] = v; bi[ii] = cj; }
            }
    }

    __syncthreads();
#pragma unroll
    for (int ii = 0; ii < 4; ++ii) {
        sred[(ty * 4 + ii) * 16 + tx]  = bv[ii];
        sredi[(ty * 4 + ii) * 16 + tx] = bi[ii];
    }
    __syncthreads();
    if (t < TM) {
        double v = sred[t * 16]; int ix = sredi[t * 16];
        for (int x = 1; x < 16; ++x) {
            double vv = sred[t * 16 + x]; int ii = sredi[t * 16 + x];
            if (vv > v || (vv == v && ii < ix)) { v = vv; ix = ii; }
        }
        pval[blockIdx.y * nA + rb + t] = v;
        pidx[blockIdx.y * nA + rb + t] = ix;
    }
}

// ---------------- K3b: reduce column-split partials ------------------------------
__global__ void k_reduce_best(const double* __restrict__ pvalA, const int* __restrict__ pidxA,
                              const double* __restrict__ pvalB, const int* __restrict__ pidxB,
                              double* __restrict__ bestSd, int* __restrict__ bestI,
                              double* __restrict__ bestPSd, int* __restrict__ bestPI) {
    int r = blockIdx.x * 256 + threadIdx.x;
    if (r >= PP) return;
    {
        double v = pvalA[r]; int ix = pidxA[r];
        for (int s = 1; s < CSPLIT; ++s) {
            double vv = pvalA[s * PP + r]; int ii = pidxA[s * PP + r];
            if (vv > v || (vv == v && ii < ix)) { v = vv; ix = ii; }
        }
        bestSd[r] = v; bestI[r] = ix;
    }
    {
        double v = pvalB[r]; int ix = pidxB[r];
        for (int s = 1; s < CSPLIT; ++s) {
            double vv = pvalB[s * NN + r]; int ii = pidxB[s * NN + r];
            if (vv > v || (vv == v && ii < ix)) { v = vv; ix = ii; }
        }
        bestPSd[r] = v; bestPI[r] = ix;
    }
}

// ---------------- K4: image sim/softmax + select output + seeding ----------------
__global__ void k_im_select(const float* __restrict__ imn,
                            const double* __restrict__ bestSd,
                            const int* __restrict__ bestI,
                            float* __restrict__ outSelect,
                            int* __restrict__ seed) {
    int p = blockIdx.x * 4 + (threadIdx.x >> 6);
    int lane = threadIdx.x & 63;
    int h = p >> 7;       // /W, W=128
    int w = p & 127;
    float2 ctr = *(const float2*)&imn[p * CC + lane * 2];

    double sim[KK];
#pragma unroll
    for (int k = 0; k < KK; ++k) {
        int di = k / 5 - 2, dj = k % 5 - 2;
        int hc = min(max(h + di, 0), HH - 1);
        int wc = min(max(w + dj, 0), WW - 1);
        int q = hc * WW + wc;
        float2 nv = *(const float2*)&imn[q * CC + lane * 2];
        double part = (double)ctr.x * (double)nv.x + (double)ctr.y * (double)nv.y;
#pragma unroll
        for (int o = 32; o; o >>= 1) part += __shfl_xor(part, o);
        sim[k] = part;
    }
    double mx = sim[0];
#pragma unroll
    for (int k = 1; k < KK; ++k) mx = fmax(mx, sim[k]);
    double sum = 0.0;
#pragma unroll
    for (int k = 0; k < KK; ++k) { sim[k] = exp(sim[k] - mx); sum += sim[k]; }
    double inv = 1.0 / sum;

    double sel[KK];
#pragma unroll
    for (int k = 0; k < KK; ++k) {
        int di = k / 5 - 2, dj = k % 5 - 2;
        int h2 = h + di, w2 = w + dj;
        bool valid = (h2 >= 0 && h2 < HH && w2 >= 0 && w2 < WW);
        int hc = min(max(h2, 0), HH - 1), wc = min(max(w2, 0), WW - 1);
        double conf = bestSd[hc * WW + wc];
        double so = valid ? (sim[k] * inv * conf) : (double)NEGV;
        if (lane == k) outSelect[k * PP + p] = (float)so;
        sel[k] = (k == 12) ? (double)NEGV : so;
    }

    // top-4 (ascending-k strict > == lax.top_k low-index tie-break)
    int tk1 = 0, tk2 = 0, tk3 = 0, tk4 = 0;
    {
        unsigned chosen = 1u << 12;
#pragma unroll
        for (int s = 0; s < 4; ++s) {
            double bvv = -1e300; int bk = 0;
#pragma unroll
            for (int k = 0; k < KK; ++k)
                if (!((chosen >> k) & 1) && sel[k] > bvv) { bvv = sel[k]; bk = k; }
            chosen |= 1u << bk;
            if (s == 0) tk1 = bk; else if (s == 1) tk2 = bk; else if (s == 2) tk3 = bk; else tk4 = bk;
        }
    }
    if (lane == 0) {
        int tks[5] = {12, tk1, tk2, tk3, tk4};
#pragma unroll
        for (int s = 0; s < 5; ++s) {
            int k = tks[s];
            int di = k / 5 - 2, dj = k % 5 - 2;
            int h2 = h + di, w2 = w + dj;
            int pix = (h2 >= 0 && h2 < HH && w2 >= 0 && w2 < WW) ? (h2 * WW + w2) : -1;
            pix = min(max(pix, 0), PP - 1);
            seed[p * SPOT + s] = bestI[pix];
        }
    }
}

// ---------------- K6: pc sim/softmax + seeding -----------------------------------
__global__ void k_pc_select(const float* __restrict__ pcn,
                            const int* __restrict__ nb,
                            const double* __restrict__ bestPSd,
                            const int* __restrict__ bestPI,
                            int* __restrict__ pcseed) {
    int i = blockIdx.x * 4 + (threadIdx.x >> 6);
    int lane = threadIdx.x & 63;
    float2 ctr = *(const float2*)&pcn[i * CC + lane * 2];

    int nbr[KK];
#pragma unroll
    for (int k = 0; k < KK; ++k) nbr[k] = nb[i * KK + k];

    double sim[KK];
#pragma unroll
    for (int k = 0; k < KK; ++k) {
        float2 nv = *(const float2*)&pcn[nbr[k] * CC + lane * 2];
        double part = (double)ctr.x * (double)nv.x + (double)ctr.y * (double)nv.y;
#pragma unroll
        for (int o = 32; o; o >>= 1) part += __shfl_xor(part, o);
        sim[k] = part;
    }
    double mx = sim[0];
#pragma unroll
    for (int k = 1; k < KK; ++k) mx = fmax(mx, sim[k]);
    double sum = 0.0;
#pragma unroll
    for (int k = 0; k < KK; ++k) { sim[k] = exp(sim[k] - mx); sum += sim[k]; }
    double inv = 1.0 / sum;

    double sel[KK];
    sel[0] = (double)NEGV;
#pragma unroll
    for (int k = 1; k < KK; ++k) sel[k] = sim[k] * inv * bestPSd[nbr[k]];

    int tk1 = 0, tk2 = 0, tk3 = 0, tk4 = 0;
    {
        unsigned chosen = 0u;
#pragma unroll
        for (int s = 0; s < 4; ++s) {
            double bvv = -1e300; int bk = 0;
#pragma unroll
            for (int k = 0; k < KK; ++k)
                if (!((chosen >> k) & 1) && sel[k] > bvv) { bvv = sel[k]; bk = k; }
            chosen |= 1u << bk;
            if (s == 0) tk1 = bk; else if (s == 1) tk2 = bk; else if (s == 2) tk3 = bk; else tk4 = bk;
        }
    }
    if (lane == 0) {
        int tks[5] = {0, tk1, tk2, tk3, tk4};
#pragma unroll
        for (int s = 0; s < 5; ++s)
            pcseed[i * SPOT + s] = bestPI[nbr[tks[s]]];
    }
}

// ---------------- bitmap -> stable top-125 compaction ----------------------------
__device__ __forceinline__ void compact_bits(const unsigned* bits, int row,
                                             float* __restrict__ maskOut,
                                             float* __restrict__ idxOut, int lane) {
    int base = 0;
    for (int w = 0; w < 160 && base < 125; ++w) {
        unsigned word = bits[w];
        int cnt = __popc(word);
        if (lane < cnt) {
            unsigned v = word;
            for (int t = 0; t < lane; ++t) v &= v - 1;
            int pos = __ffs((int)v) - 1;
            idxOut[row * 125 + base + lane]  = (float)(w * 32 + pos);
            maskOut[row * 125 + base + lane] = 1.0f;
        }
        base += cnt;
    }
    for (int w = 0; w < 160 && base < 125; ++w) {
        unsigned word = ~bits[w];
        int cnt = __popc(word);
        int take = min(cnt, 125 - base);
        if (lane < take) {
            unsigned v = word;
            for (int t = 0; t < lane; ++t) v &= v - 1;
            int pos = __ffs((int)v) - 1;
            idxOut[row * 125 + base + lane]  = (float)(w * 32 + pos);
            maskOut[row * 125 + base + lane] = 0.0f;
        }
        base += take;
    }
}

// ---------------- K5: im spoting ------------------------------------------------
__global__ void k_im_spot(const int* __restrict__ seed, const int* __restrict__ nb,
                          float* __restrict__ maskOut, float* __restrict__ idxOut) {
    __shared__ unsigned bits[4][160];
    int wid = threadIdx.x >> 6, lane = threadIdx.x & 63;
    int p = blockIdx.x * 4 + wid;
    for (int w = lane; w < 160; w += 64) bits[wid][w] = 0u;
    __syncthreads();
    for (int e = lane; e < 125; e += 64) {
        int sd = seed[p * SPOT + e / 25];
        int pt = nb[sd * KK + (e % 25)];
        atomicOr(&bits[wid][pt >> 5], 1u << (pt & 31));
    }
    __syncthreads();
    compact_bits(bits[wid], p, maskOut, idxOut, lane);
}

// ---------------- K7: pc spoting ------------------------------------------------
__global__ void k_pc_spot(const int* __restrict__ pcseed,
                          float* __restrict__ maskOut, float* __restrict__ idxOut) {
    __shared__ unsigned bits[4][160];
    int wid = threadIdx.x >> 6, lane = threadIdx.x & 63;
    int i = blockIdx.x * 4 + wid;
    for (int w = lane; w < 160; w += 64) bits[wid][w] = 0u;
    __syncthreads();
    for (int e = lane; e < 125; e += 64) {
        int q = pcseed[i * SPOT + e / 25];
        int kk = e % 25;
        int r0 = q >> 7, c0 = q & 127;
        int r = min(max(r0 + kk / 5 - 2, 0), HH - 1);
        int c = min(max(c0 + kk % 5 - 2, 0), WW - 1);
        int pix = r * WW + c;
        atomicOr(&bits[wid][pix >> 5], 1u << (pix & 31));
    }
    __syncthreads();
    compact_bits(bits[wid], i, maskOut, idxOut, lane);
}

// ---------------- host ----------------------------------------------------------
extern "C" void kernel_launch(void* const* d_in, const int* in_sizes, int n_in,
                              void* d_out, int out_size, void* d_ws, size_t ws_size,
                              hipStream_t stream) {
    const float* imf = (const float*)d_in[0];
    const float* pcf = (const float*)d_in[1];
    const float* pts = (const float*)d_in[2];
    float* out = (float*)d_out;

    char* w = (char*)d_ws;
    double* bestSd  = (double*)w;  w += (size_t)PP * 8;
    double* bestPSd = (double*)w;  w += (size_t)NN * 8;
    double* pvalA   = (double*)w;  w += (size_t)CSPLIT * PP * 8;
    double* pvalB   = (double*)w;  w += (size_t)CSPLIT * NN * 8;
    float*  imn     = (float*)w;   w += (size_t)PP * CC * 4;
    float*  pcn     = (float*)w;   w += (size_t)NN * CC * 4;
    int*    nb      = (int*)w;     w += (size_t)NN * KK * 4;
    int*    bestI   = (int*)w;     w += (size_t)PP * 4;
    int*    bestPI  = (int*)w;     w += (size_t)NN * 4;
    int*    pidxA   = (int*)w;     w += (size_t)CSPLIT * PP * 4;
    int*    pidxB   = (int*)w;     w += (size_t)CSPLIT * NN * 4;
    int*    seed    = (int*)w;     w += (size_t)PP * SPOT * 4;
    int*    pcseed  = (int*)w;     w += (size_t)NN * SPOT * 4;

    float* outSelect = out;                       // (25, 5120)
    float* outMask   = out + KK * PP;             // (5120, 125)
    float* outIdx    = outMask + PP * 125;        // (5120, 125)
    float* outIdxPc  = outIdx + PP * 125;         // (5120, 125)
    float* outMaskPc = outIdxPc + NN * 125;       // (5120, 125)

    k_normalize<<<(PP + NN) / 4, 256, 0, stream>>>(imf, pcf, imn, pcn);
    k_knn<<<NN, 256, 0, stream>>>(pts, nb);
    k_rowmax<<<dim3(PP / TM, CSPLIT), 256, 0, stream>>>(imn, pcn, NN, pvalA, pidxA, PP);
    k_rowmax<<<dim3(NN / TM, CSPLIT), 256, 0, stream>>>(pcn, imn, PP, pvalB, pidxB, NN);
    k_reduce_best<<<PP / 256, 256, 0, stream>>>(pvalA, pidxA, pvalB, pidxB,
                                                bestSd, bestI, bestPSd, bestPI);
    k_im_select<<<PP / 4, 256, 0, stream>>>(imn, bestSd, bestI, outSelect, seed);
    k_pc_select<<<NN / 4, 256, 0, stream>>>(pcn, nb, bestPSd, bestPI, pcseed);
    k_im_spot<<<PP / 4, 256, 0, stream>>>(seed, nb, outMask, outIdx);
    k_pc_spot<<<NN / 4, 256, 0, stream>>>(pcseed, outMaskPc, outIdxPc);
}

// Round 3
// 675.322 us; speedup vs baseline: 2.1873x; 1.2352x over previous
//
#include <hip/hip_runtime.h>
#include <float.h>
#include <math.h>

#define HH 40
#define WW 128
#define PP 5120
#define NN 5120
#define CC 128
#define KK 25
#define SPOT 5
#define NEGV -1e8f

#define TM 64
#define TN 64
#define CSPLIT 16

// ---------------- K1: L2-normalize rows (fp64 norm, fp32 stored) ----------------
__global__ void k_normalize(const float* __restrict__ imf, const float* __restrict__ pcf,
                            float* __restrict__ imn, float* __restrict__ pcn) {
    int row = blockIdx.x * 4 + (threadIdx.x >> 6);
    int lane = threadIdx.x & 63;
    const float* src; float* dst; int r;
    if (row < PP) { src = imf; dst = imn; r = row; }
    else          { src = pcf; dst = pcn; r = row - PP; }
    float2 v = *(const float2*)&src[r * CC + lane * 2];
    double ss = (double)v.x * (double)v.x + (double)v.y * (double)v.y;
#pragma unroll
    for (int o = 32; o; o >>= 1) ss += __shfl_xor(ss, o);
    double inv = 1.0 / fmax(sqrt(ss), 1e-12);
    float2 o2 = make_float2((float)((double)v.x * inv), (float)((double)v.y * inv));
    *(float2*)&dst[r * CC + lane * 2] = o2;
}

// ---------------- K2: KNN top-25, register-tournament version --------------------
__global__ __launch_bounds__(256) void k_knn(const float* __restrict__ pts,
                                             int* __restrict__ nb) {
    __shared__ double sv[2][4];
    __shared__ int    si[2][4];
    int i = blockIdx.x;
    int t = threadIdx.x;
    int wid = t >> 6, lane = t & 63;
    double px = pts[i * 3 + 0], py = pts[i * 3 + 1], pz = pts[i * 3 + 2];

    double d[20];
    int base = t * 20;
    double lv = DBL_MAX; int li = 0x7fffffff;
#pragma unroll
    for (int e = 0; e < 20; ++e) {
        int j = base + e;
        double dx = px - (double)pts[j * 3 + 0];
        double dy = py - (double)pts[j * 3 + 1];
        double dz = pz - (double)pts[j * 3 + 2];
        double v = dx * dx + dy * dy + dz * dz;
        d[e] = v;
        if (v < lv) { lv = v; li = j; }   // ascending e => low-index tie-break
    }

    unsigned removed = 0u;
    for (int it = 0; it < KK; ++it) {
        double bv = lv; int bi = li;
#pragma unroll
        for (int o = 32; o; o >>= 1) {
            double ov = __shfl_xor(bv, o); int oi = __shfl_xor(bi, o);
            if (ov < bv || (ov == bv && oi < bi)) { bv = ov; bi = oi; }
        }
        int par = it & 1;
        if (lane == 0) { sv[par][wid] = bv; si[par][wid] = bi; }
        __syncthreads();
        bv = sv[par][0]; bi = si[par][0];
#pragma unroll
        for (int wv = 1; wv < 4; ++wv) {
            double ov = sv[par][wv]; int oi = si[par][wv];
            if (ov < bv || (ov == bv && oi < bi)) { bv = ov; bi = oi; }
        }
        if (t == 0) nb[i * KK + it] = bi;
        if (bi >= base && bi < base + 20) {
            removed |= 1u << (bi - base);
            lv = DBL_MAX; li = 0x7fffffff;
#pragma unroll
            for (int e = 0; e < 20; ++e) {
                bool alive = !((removed >> e) & 1u);
                if (alive && d[e] < lv) { lv = d[e]; li = base + e; }
            }
        }
    }
}

// ---------------- K3: tiled cosine row-max/argmax (fp64 accumulate) --------------
// LDS tiles are row-major [row][c] with XOR swizzle c' = c ^ (((row>>2)&7)<<2):
// staging writes are contiguous float4 (conflict-free); float4 reads along c
// alias at most 2-way (free). No transposed scalar stores.
__global__ __launch_bounds__(256, 2) void k_rowmax(const float* __restrict__ A,
                                                   const float* __restrict__ B,
                                                   int nB,
                                                   double* __restrict__ pval,
                                                   int* __restrict__ pidx,
                                                   int nA) {
    __shared__ float As[TM * CC];
    __shared__ float Bs[TN * CC];

    int t = threadIdx.x;
    int rb = blockIdx.x * TM;
    int segLen = nB / CSPLIT;
    int segBase = blockIdx.y * segLen;

    // stage A tile, row-major swizzled
    for (int q = t; q < TM * CC / 4; q += 256) {
        int row = q >> 5;      // CC/4 = 32 float4 per row
        int c4 = q & 31;
        float4 v = *(const float4*)&A[(rb + row) * CC + c4 * 4];
        int sw = ((row >> 2) & 7) << 2;
        *(float4*)&As[row * CC + ((c4 * 4) ^ sw)] = v;
    }

    int ty = t >> 4, tx = t & 15;     // ty: 0..15 row-groups, tx: 0..15 col-groups
    int swA = (ty & 7) << 2;
    int swB = (tx & 7) << 2;

    double bv[4] = {-1e300, -1e300, -1e300, -1e300};
    int    bi[4] = {0, 0, 0, 0};

    for (int ch = 0; ch < segLen; ch += TN) {
        __syncthreads();
        for (int q = t; q < TN * CC / 4; q += 256) {
            int row = q >> 5;
            int c4 = q & 31;
            float4 v = *(const float4*)&B[(segBase + ch + row) * CC + c4 * 4];
            int sw = ((row >> 2) & 7) << 2;
            *(float4*)&Bs[row * CC + ((c4 * 4) ^ sw)] = v;
        }
        __syncthreads();

        double acc[4][4];
#pragma unroll
        for (int ii = 0; ii < 4; ++ii)
#pragma unroll
            for (int jj = 0; jj < 4; ++jj) acc[ii][jj] = 0.0;

#pragma unroll 2
        for (int cs = 0; cs < CC / 4; ++cs) {
            int c = cs << 2;
            float4 af[4], bf[4];
#pragma unroll
            for (int ii = 0; ii < 4; ++ii)
                af[ii] = *(const float4*)&As[(ty * 4 + ii) * CC + (c ^ swA)];
#pragma unroll
            for (int jj = 0; jj < 4; ++jj)
                bf[jj] = *(const float4*)&Bs[(tx * 4 + jj) * CC + (c ^ swB)];

            double da[4][4], db[4][4];
#pragma unroll
            for (int ii = 0; ii < 4; ++ii) {
                da[ii][0] = af[ii].x; da[ii][1] = af[ii].y;
                da[ii][2] = af[ii].z; da[ii][3] = af[ii].w;
            }
#pragma unroll
            for (int jj = 0; jj < 4; ++jj) {
                db[jj][0] = bf[jj].x; db[jj][1] = bf[jj].y;
                db[jj][2] = bf[jj].z; db[jj][3] = bf[jj].w;
            }
#pragma unroll
            for (int ii = 0; ii < 4; ++ii)
#pragma unroll
                for (int jj = 0; jj < 4; ++jj) {
                    acc[ii][jj] += da[ii][0] * db[jj][0];
                    acc[ii][jj] += da[ii][1] * db[jj][1];
                    acc[ii][jj] += da[ii][2] * db[jj][2];
                    acc[ii][jj] += da[ii][3] * db[jj][3];
                }
        }

        int cb = segBase + ch + tx * 4;
#pragma unroll
        for (int ii = 0; ii < 4; ++ii)
#pragma unroll
            for (int jj = 0; jj < 4; ++jj) {
                double v = acc[ii][jj];
                int cj = cb + jj;
                if (v > bv[ii] || (v == bv[ii] && cj < bi[ii])) { bv[ii] = v; bi[ii] = cj; }
            }
    }

    // cross-tx argmax reduce within the 16-lane group (no LDS)
#pragma unroll
    for (int ii = 0; ii < 4; ++ii) {
        double v = bv[ii]; int ix = bi[ii];
#pragma unroll
        for (int o = 1; o < 16; o <<= 1) {
            double ov = __shfl_xor(v, o);
            int oi = __shfl_xor(ix, o);
            if (ov > v || (ov == v && oi < ix)) { v = ov; ix = oi; }
        }
        if (tx == 0) {
            pval[blockIdx.y * nA + rb + ty * 4 + ii] = v;
            pidx[blockIdx.y * nA + rb + ty * 4 + ii] = ix;
        }
    }
}

// ---------------- K3b: reduce column-split partials ------------------------------
__global__ void k_reduce_best(const double* __restrict__ pvalA, const int* __restrict__ pidxA,
                              const double* __restrict__ pvalB, const int* __restrict__ pidxB,
                              double* __restrict__ bestSd, int* __restrict__ bestI,
                              double* __restrict__ bestPSd, int* __restrict__ bestPI) {
    int r = blockIdx.x * 256 + threadIdx.x;
    if (r >= PP) return;
    {
        double v = pvalA[r]; int ix = pidxA[r];
        for (int s = 1; s < CSPLIT; ++s) {
            double vv = pvalA[s * PP + r]; int ii = pidxA[s * PP + r];
            if (vv > v || (vv == v && ii < ix)) { v = vv; ix = ii; }
        }
        bestSd[r] = v; bestI[r] = ix;
    }
    {
        double v = pvalB[r]; int ix = pidxB[r];
        for (int s = 1; s < CSPLIT; ++s) {
            double vv = pvalB[s * NN + r]; int ii = pidxB[s * NN + r];
            if (vv > v || (vv == v && ii < ix)) { v = vv; ix = ii; }
        }
        bestPSd[r] = v; bestPI[r] = ix;
    }
}

// ---------------- K4: image sim/softmax + select output + seeding ----------------
__global__ void k_im_select(const float* __restrict__ imn,
                            const double* __restrict__ bestSd,
                            const int* __restrict__ bestI,
                            float* __restrict__ outSelect,
                            int* __restrict__ seed) {
    int p = blockIdx.x * 4 + (threadIdx.x >> 6);
    int lane = threadIdx.x & 63;
    int h = p >> 7;       // /W, W=128
    int w = p & 127;
    float2 ctr = *(const float2*)&imn[p * CC + lane * 2];

    double sim[KK];
#pragma unroll
    for (int k = 0; k < KK; ++k) {
        int di = k / 5 - 2, dj = k % 5 - 2;
        int hc = min(max(h + di, 0), HH - 1);
        int wc = min(max(w + dj, 0), WW - 1);
        int q = hc * WW + wc;
        float2 nv = *(const float2*)&imn[q * CC + lane * 2];
        double part = (double)ctr.x * (double)nv.x + (double)ctr.y * (double)nv.y;
#pragma unroll
        for (int o = 32; o; o >>= 1) part += __shfl_xor(part, o);
        sim[k] = part;
    }
    double mx = sim[0];
#pragma unroll
    for (int k = 1; k < KK; ++k) mx = fmax(mx, sim[k]);
    double sum = 0.0;
#pragma unroll
    for (int k = 0; k < KK; ++k) { sim[k] = exp(sim[k] - mx); sum += sim[k]; }
    double inv = 1.0 / sum;

    double sel[KK];
#pragma unroll
    for (int k = 0; k < KK; ++k) {
        int di = k / 5 - 2, dj = k % 5 - 2;
        int h2 = h + di, w2 = w + dj;
        bool valid = (h2 >= 0 && h2 < HH && w2 >= 0 && w2 < WW);
        int hc = min(max(h2, 0), HH - 1), wc = min(max(w2, 0), WW - 1);
        double conf = bestSd[hc * WW + wc];
        double so = valid ? (sim[k] * inv * conf) : (double)NEGV;
        if (lane == k) outSelect[k * PP + p] = (float)so;
        sel[k] = (k == 12) ? (double)NEGV : so;
    }

    // top-4 (ascending-k strict > == lax.top_k low-index tie-break)
    int tk1 = 0, tk2 = 0, tk3 = 0, tk4 = 0;
    {
        unsigned chosen = 1u << 12;
#pragma unroll
        for (int s = 0; s < 4; ++s) {
            double bvv = -1e300; int bk = 0;
#pragma unroll
            for (int k = 0; k < KK; ++k)
                if (!((chosen >> k) & 1) && sel[k] > bvv) { bvv = sel[k]; bk = k; }
            chosen |= 1u << bk;
            if (s == 0) tk1 = bk; else if (s == 1) tk2 = bk; else if (s == 2) tk3 = bk; else tk4 = bk;
        }
    }
    if (lane == 0) {
        int tks[5] = {12, tk1, tk2, tk3, tk4};
#pragma unroll
        for (int s = 0; s < 5; ++s) {
            int k = tks[s];
            int di = k / 5 - 2, dj = k % 5 - 2;
            int h2 = h + di, w2 = w + dj;
            int pix = (h2 >= 0 && h2 < HH && w2 >= 0 && w2 < WW) ? (h2 * WW + w2) : -1;
            pix = min(max(pix, 0), PP - 1);
            seed[p * SPOT + s] = bestI[pix];
        }
    }
}

// ---------------- K6: pc sim/softmax + seeding -----------------------------------
__global__ void k_pc_select(const float* __restrict__ pcn,
                            const int* __restrict__ nb,
                            const double* __restrict__ bestPSd,
                            const int* __restrict__ bestPI,
                            int* __restrict__ pcseed) {
    int i = blockIdx.x * 4 + (threadIdx.x >> 6);
    int lane = threadIdx.x & 63;
    float2 ctr = *(const float2*)&pcn[i * CC + lane * 2];

    int nbr[KK];
#pragma unroll
    for (int k = 0; k < KK; ++k) nbr[k] = nb[i * KK + k];

    double sim[KK];
#pragma unroll
    for (int k = 0; k < KK; ++k) {
        float2 nv = *(const float2*)&pcn[nbr[k] * CC + lane * 2];
        double part = (double)ctr.x * (double)nv.x + (double)ctr.y * (double)nv.y;
#pragma unroll
        for (int o = 32; o; o >>= 1) part += __shfl_xor(part, o);
        sim[k] = part;
    }
    double mx = sim[0];
#pragma unroll
    for (int k = 1; k < KK; ++k) mx = fmax(mx, sim[k]);
    double sum = 0.0;
#pragma unroll
    for (int k = 0; k < KK; ++k) { sim[k] = exp(sim[k] - mx); sum += sim[k]; }
    double inv = 1.0 / sum;

    double sel[KK];
    sel[0] = (double)NEGV;
#pragma unroll
    for (int k = 1; k < KK; ++k) sel[k] = sim[k] * inv * bestPSd[nbr[k]];

    int tk1 = 0, tk2 = 0, tk3 = 0, tk4 = 0;
    {
        unsigned chosen = 0u;
#pragma unroll
        for (int s = 0; s < 4; ++s) {
            double bvv = -1e300; int bk = 0;
#pragma unroll
            for (int k = 0; k < KK; ++k)
                if (!((chosen >> k) & 1) && sel[k] > bvv) { bvv = sel[k]; bk = k; }
            chosen |= 1u << bk;
            if (s == 0) tk1 = bk; else if (s == 1) tk2 = bk; else if (s == 2) tk3 = bk; else tk4 = bk;
        }
    }
    if (lane == 0) {
        int tks[5] = {0, tk1, tk2, tk3, tk4};
#pragma unroll
        for (int s = 0; s < 5; ++s)
            pcseed[i * SPOT + s] = bestPI[nbr[tks[s]]];
    }
}

// ---------------- bitmap -> stable top-125 compaction ----------------------------
__device__ __forceinline__ void compact_bits(const unsigned* bits, int row,
                                             float* __restrict__ maskOut,
                                             float* __restrict__ idxOut, int lane) {
    int base = 0;
    for (int w = 0; w < 160 && base < 125; ++w) {
        unsigned word = bits[w];
        int cnt = __popc(word);
        if (lane < cnt) {
            unsigned v = word;
            for (int t = 0; t < lane; ++t) v &= v - 1;
            int pos = __ffs((int)v) - 1;
            idxOut[row * 125 + base + lane]  = (float)(w * 32 + pos);
            maskOut[row * 125 + base + lane] = 1.0f;
        }
        base += cnt;
    }
    for (int w = 0; w < 160 && base < 125; ++w) {
        unsigned word = ~bits[w];
        int cnt = __popc(word);
        int take = min(cnt, 125 - base);
        if (lane < take) {
            unsigned v = word;
            for (int t = 0; t < lane; ++t) v &= v - 1;
            int pos = __ffs((int)v) - 1;
            idxOut[row * 125 + base + lane]  = (float)(w * 32 + pos);
            maskOut[row * 125 + base + lane] = 0.0f;
        }
        base += take;
    }
}

// ---------------- K5: im spoting ------------------------------------------------
__global__ void k_im_spot(const int* __restrict__ seed, const int* __restrict__ nb,
                          float* __restrict__ maskOut, float* __restrict__ idxOut) {
    __shared__ unsigned bits[4][160];
    int wid = threadIdx.x >> 6, lane = threadIdx.x & 63;
    int p = blockIdx.x * 4 + wid;
    for (int w = lane; w < 160; w += 64) bits[wid][w] = 0u;
    __syncthreads();
    for (int e = lane; e < 125; e += 64) {
        int sd = seed[p * SPOT + e / 25];
        int pt = nb[sd * KK + (e % 25)];
        atomicOr(&bits[wid][pt >> 5], 1u << (pt & 31));
    }
    __syncthreads();
    compact_bits(bits[wid], p, maskOut, idxOut, lane);
}

// ---------------- K7: pc spoting ------------------------------------------------
__global__ void k_pc_spot(const int* __restrict__ pcseed,
                          float* __restrict__ maskOut, float* __restrict__ idxOut) {
    __shared__ unsigned bits[4][160];
    int wid = threadIdx.x >> 6, lane = threadIdx.x & 63;
    int i = blockIdx.x * 4 + wid;
    for (int w = lane; w < 160; w += 64) bits[wid][w] = 0u;
    __syncthreads();
    for (int e = lane; e < 125; e += 64) {
        int q = pcseed[i * SPOT + e / 25];
        int kk = e % 25;
        int r0 = q >> 7, c0 = q & 127;
        int r = min(max(r0 + kk / 5 - 2, 0), HH - 1);
        int c = min(max(c0 + kk % 5 - 2, 0), WW - 1);
        int pix = r * WW + c;
        atomicOr(&bits[wid][pix >> 5], 1u << (pix & 31));
    }
    __syncthreads();
    compact_bits(bits[wid], i, maskOut, idxOut, lane);
}

// ---------------- host ----------------------------------------------------------
extern "C" void kernel_launch(void* const* d_in, const int* in_sizes, int n_in,
                              void* d_out, int out_size, void* d_ws, size_t ws_size,
                              hipStream_t stream) {
    const float* imf = (const float*)d_in[0];
    const float* pcf = (const float*)d_in[1];
    const float* pts = (const float*)d_in[2];
    float* out = (float*)d_out;

    char* w = (char*)d_ws;
    double* bestSd  = (double*)w;  w += (size_t)PP * 8;
    double* bestPSd = (double*)w;  w += (size_t)NN * 8;
    double* pvalA   = (double*)w;  w += (size_t)CSPLIT * PP * 8;
    double* pvalB   = (double*)w;  w += (size_t)CSPLIT * NN * 8;
    float*  imn     = (float*)w;   w += (size_t)PP * CC * 4;
    float*  pcn     = (float*)w;   w += (size_t)NN * CC * 4;
    int*    nb      = (int*)w;     w += (size_t)NN * KK * 4;
    int*    bestI   = (int*)w;     w += (size_t)PP * 4;
    int*    bestPI  = (int*)w;     w += (size_t)NN * 4;
    int*    pidxA   = (int*)w;     w += (size_t)CSPLIT * PP * 4;
    int*    pidxB   = (int*)w;     w += (size_t)CSPLIT * NN * 4;
    int*    seed    = (int*)w;     w += (size_t)PP * SPOT * 4;
    int*    pcseed  = (int*)w;     w += (size_t)NN * SPOT * 4;

    float* outSelect = out;                       // (25, 5120)
    float* outMask   = out + KK * PP;             // (5120, 125)
    float* outIdx    = outMask + PP * 125;        // (5120, 125)
    float* outIdxPc  = outIdx + PP * 125;         // (5120, 125)
    float* outMaskPc = outIdxPc + NN * 125;       // (5120, 125)

    k_normalize<<<(PP + NN) / 4, 256, 0, stream>>>(imf, pcf, imn, pcn);
    k_knn<<<NN, 256, 0, stream>>>(pts, nb);
    k_rowmax<<<dim3(PP / TM, CSPLIT), 256, 0, stream>>>(imn, pcn, NN, pvalA, pidxA, PP);
    k_rowmax<<<dim3(NN / TM, CSPLIT), 256, 0, stream>>>(pcn, imn, PP, pvalB, pidxB, NN);
    k_reduce_best<<<PP / 256, 256, 0, stream>>>(pvalA, pidxA, pvalB, pidxB,
                                                bestSd, bestI, bestPSd, bestPI);
    k_im_select<<<PP / 4, 256, 0, stream>>>(imn, bestSd, bestI, outSelect, seed);
    k_pc_select<<<NN / 4, 256, 0, stream>>>(pcn, nb, bestPSd, bestPI, pcseed);
    k_im_spot<<<PP / 4, 256, 0, stream>>>(seed, nb, outMask, outIdx);
    k_pc_spot<<<NN / 4, 256, 0, stream>>>(pcseed, outMaskPc, outIdxPc);
}

// Round 4
// 631.610 us; speedup vs baseline: 2.3387x; 1.0692x over previous
//
#include <hip/hip_runtime.h>
#include <float.h>
#include <math.h>

#define HH 40
#define WW 128
#define PP 5120
#define NN 5120
#define CC 128
#define KK 25
#define SPOT 5
#define NEGV -1e8f

#define TM 64
#define TN 64
#define CSPLIT 16
#define EPS_GAP 1e-4f   // >> worst-case fp32 dot error (7.6e-6) for unit vectors

// ---------------- K1: L2-normalize rows (fp64 norm, fp32 stored) ----------------
__global__ void k_normalize(const float* __restrict__ imf, const float* __restrict__ pcf,
                            float* __restrict__ imn, float* __restrict__ pcn) {
    int row = blockIdx.x * 4 + (threadIdx.x >> 6);
    int lane = threadIdx.x & 63;
    const float* src; float* dst; int r;
    if (row < PP) { src = imf; dst = imn; r = row; }
    else          { src = pcf; dst = pcn; r = row - PP; }
    float2 v = *(const float2*)&src[r * CC + lane * 2];
    double ss = (double)v.x * (double)v.x + (double)v.y * (double)v.y;
#pragma unroll
    for (int o = 32; o; o >>= 1) ss += __shfl_xor(ss, o);
    double inv = 1.0 / fmax(sqrt(ss), 1e-12);
    float2 o2 = make_float2((float)((double)v.x * inv), (float)((double)v.y * inv));
    *(float2*)&dst[r * CC + lane * 2] = o2;
}

// ---------------- K2: KNN top-25, register-tournament version --------------------
__global__ __launch_bounds__(256) void k_knn(const float* __restrict__ pts,
                                             int* __restrict__ nb) {
    __shared__ double sv[2][4];
    __shared__ int    si[2][4];
    int i = blockIdx.x;
    int t = threadIdx.x;
    int wid = t >> 6, lane = t & 63;
    double px = pts[i * 3 + 0], py = pts[i * 3 + 1], pz = pts[i * 3 + 2];

    double d[20];
    int base = t * 20;
    double lv = DBL_MAX; int li = 0x7fffffff;
#pragma unroll
    for (int e = 0; e < 20; ++e) {
        int j = base + e;
        double dx = px - (double)pts[j * 3 + 0];
        double dy = py - (double)pts[j * 3 + 1];
        double dz = pz - (double)pts[j * 3 + 2];
        double v = dx * dx + dy * dy + dz * dz;
        d[e] = v;
        if (v < lv) { lv = v; li = j; }   // ascending e => low-index tie-break
    }

    unsigned removed = 0u;
    for (int it = 0; it < KK; ++it) {
        double bv = lv; int bi = li;
#pragma unroll
        for (int o = 32; o; o >>= 1) {
            double ov = __shfl_xor(bv, o); int oi = __shfl_xor(bi, o);
            if (ov < bv || (ov == bv && oi < bi)) { bv = ov; bi = oi; }
        }
        int par = it & 1;
        if (lane == 0) { sv[par][wid] = bv; si[par][wid] = bi; }
        __syncthreads();
        bv = sv[par][0]; bi = si[par][0];
#pragma unroll
        for (int wv = 1; wv < 4; ++wv) {
            double ov = sv[par][wv]; int oi = si[par][wv];
            if (ov < bv || (ov == bv && oi < bi)) { bv = ov; bi = oi; }
        }
        if (t == 0) nb[i * KK + it] = bi;
        if (bi >= base && bi < base + 20) {
            removed |= 1u << (bi - base);
            lv = DBL_MAX; li = 0x7fffffff;
#pragma unroll
            for (int e = 0; e < 20; ++e) {
                bool alive = !((removed >> e) & 1u);
                if (alive && d[e] < lv) { lv = d[e]; li = base + e; }
            }
        }
    }
}

// ---------------- K3: fp32 tiled cosine row-max/arg + top-2 gap tracking ---------
// blockIdx.z = 0: rows=imn cols=pcn ; z = 1: rows=pcn cols=imn.
// fp32 accumulate; per-row (best, second-best, argmax). Rows whose final gap
// < EPS_GAP are re-solved exactly in fp64 by k_recheck.
__global__ __launch_bounds__(256, 2) void k_rowmax(const float* __restrict__ imn,
                                                   const float* __restrict__ pcn,
                                                   float* __restrict__ pval,
                                                   float* __restrict__ pv2,
                                                   int* __restrict__ pidx) {
    const float* A = (blockIdx.z == 0) ? imn : pcn;
    const float* B = (blockIdx.z == 0) ? pcn : imn;
    __shared__ float As[TM * CC];
    __shared__ float Bs[TN * CC];

    int t = threadIdx.x;
    int rb = blockIdx.x * TM;
    const int segLen = NN / CSPLIT;
    int segBase = blockIdx.y * segLen;

    for (int q = t; q < TM * CC / 4; q += 256) {
        int row = q >> 5;
        int c4 = q & 31;
        float4 v = *(const float4*)&A[(rb + row) * CC + c4 * 4];
        int sw = ((row >> 2) & 7) << 2;
        *(float4*)&As[row * CC + ((c4 * 4) ^ sw)] = v;
    }

    int ty = t >> 4, tx = t & 15;
    int swA = (ty & 7) << 2;
    int swB = (tx & 7) << 2;

    float bv[4]  = {-1e30f, -1e30f, -1e30f, -1e30f};
    float bv2[4] = {-1e30f, -1e30f, -1e30f, -1e30f};
    int   bi[4]  = {0, 0, 0, 0};

    for (int ch = 0; ch < segLen; ch += TN) {
        __syncthreads();
        for (int q = t; q < TN * CC / 4; q += 256) {
            int row = q >> 5;
            int c4 = q & 31;
            float4 v = *(const float4*)&B[(segBase + ch + row) * CC + c4 * 4];
            int sw = ((row >> 2) & 7) << 2;
            *(float4*)&Bs[row * CC + ((c4 * 4) ^ sw)] = v;
        }
        __syncthreads();

        float acc[4][4];
#pragma unroll
        for (int ii = 0; ii < 4; ++ii)
#pragma unroll
            for (int jj = 0; jj < 4; ++jj) acc[ii][jj] = 0.0f;

#pragma unroll 4
        for (int cs = 0; cs < CC / 4; ++cs) {
            int c = cs << 2;
            float4 af[4], bf[4];
#pragma unroll
            for (int ii = 0; ii < 4; ++ii)
                af[ii] = *(const float4*)&As[(ty * 4 + ii) * CC + (c ^ swA)];
#pragma unroll
            for (int jj = 0; jj < 4; ++jj)
                bf[jj] = *(const float4*)&Bs[(tx * 4 + jj) * CC + (c ^ swB)];
#pragma unroll
            for (int ii = 0; ii < 4; ++ii)
#pragma unroll
                for (int jj = 0; jj < 4; ++jj) {
                    acc[ii][jj] += af[ii].x * bf[jj].x;
                    acc[ii][jj] += af[ii].y * bf[jj].y;
                    acc[ii][jj] += af[ii].z * bf[jj].z;
                    acc[ii][jj] += af[ii].w * bf[jj].w;
                }
        }

        int cb = segBase + ch + tx * 4;
#pragma unroll
        for (int ii = 0; ii < 4; ++ii)
#pragma unroll
            for (int jj = 0; jj < 4; ++jj) {
                float v = acc[ii][jj];
                int cj = cb + jj;
                if (v > bv[ii]) { bv2[ii] = bv[ii]; bv[ii] = v; bi[ii] = cj; }
                else {
                    bv2[ii] = fmaxf(bv2[ii], v);   // v==bv -> gap 0 -> recheck
                    if (v == bv[ii] && cj < bi[ii]) bi[ii] = cj;
                }
            }
    }

    // cross-tx top-2 merge within 16-lane group
#pragma unroll
    for (int ii = 0; ii < 4; ++ii) {
        float v1 = bv[ii], v2 = bv2[ii]; int i1 = bi[ii];
#pragma unroll
        for (int o = 1; o < 16; o <<= 1) {
            float ov1 = __shfl_xor(v1, o);
            float ov2 = __shfl_xor(v2, o);
            int   oi  = __shfl_xor(i1, o);
            if (ov1 > v1 || (ov1 == v1 && oi < i1)) {
                v2 = fmaxf(v1, ov2); v1 = ov1; i1 = oi;
            } else {
                v2 = fmaxf(v2, ov1);
            }
        }
        if (tx == 0) {
            size_t o = (size_t)blockIdx.z * CSPLIT * PP + (size_t)blockIdx.y * PP
                     + rb + ty * 4 + ii;
            pval[o] = v1; pv2[o] = v2; pidx[o] = i1;
        }
    }
}

// ---------------- K3b: reduce split partials, flag ambiguous rows ----------------
__global__ void k_reduce_best(const float* __restrict__ pval, const float* __restrict__ pv2,
                              const int* __restrict__ pidx,
                              double* __restrict__ bestSd, int* __restrict__ bestI,
                              double* __restrict__ bestPSd, int* __restrict__ bestPI,
                              int* __restrict__ list, int* __restrict__ cnt) {
    int r = blockIdx.x * 256 + threadIdx.x;
    int side = blockIdx.y;
    size_t base = (size_t)side * CSPLIT * PP + r;
    float v1 = pval[base], v2 = pv2[base]; int i1 = pidx[base];
    for (int s = 1; s < CSPLIT; ++s) {
        float ov1 = pval[base + (size_t)s * PP];
        float ov2 = pv2[base + (size_t)s * PP];
        int   oi  = pidx[base + (size_t)s * PP];
        if (ov1 > v1 || (ov1 == v1 && oi < i1)) {
            v2 = fmaxf(v1, ov2); v1 = ov1; i1 = oi;
        } else {
            v2 = fmaxf(v2, ov1);
        }
    }
    if (side == 0) { bestSd[r] = (double)v1; bestI[r] = i1; }
    else           { bestPSd[r] = (double)v1; bestPI[r] = i1; }
    if (v1 - v2 < EPS_GAP) {
        int slot = atomicAdd(cnt, 1);
        list[slot] = r | (side << 16);
    }
}

// ---------------- K3c: exact fp64 repair of ambiguous rows -----------------------
__global__ void k_recheck(const float* __restrict__ imn, const float* __restrict__ pcn,
                          const int* __restrict__ list, const int* __restrict__ cnt,
                          double* __restrict__ bestSd, int* __restrict__ bestI,
                          double* __restrict__ bestPSd, int* __restrict__ bestPI) {
    __shared__ double ad[CC];
    __shared__ double rv[4];
    __shared__ int    ri[4];
    int t = threadIdx.x;
    int wid = t >> 6, lane = t & 63;
    int total = *cnt;
    for (int e = blockIdx.x; e < total; e += gridDim.x) {
        __syncthreads();
        int ent = list[e];
        int r = ent & 0xffff, side = ent >> 16;
        const float* Arow = (side == 0 ? imn : pcn) + (size_t)r * CC;
        const float* B    = (side == 0 ? pcn : imn);
        if (t < CC) ad[t] = (double)Arow[t];
        __syncthreads();
        double bv = -1e300; int bi = 0x7fffffff;
        for (int j = t; j < NN; j += 256) {
            double s = 0.0;
#pragma unroll 8
            for (int c4 = 0; c4 < CC / 4; ++c4) {
                float4 b = *(const float4*)&B[(size_t)j * CC + c4 * 4];
                s += ad[c4 * 4 + 0] * (double)b.x;
                s += ad[c4 * 4 + 1] * (double)b.y;
                s += ad[c4 * 4 + 2] * (double)b.z;
                s += ad[c4 * 4 + 3] * (double)b.w;
            }
            if (s > bv || (s == bv && j < bi)) { bv = s; bi = j; }
        }
#pragma unroll
        for (int o = 32; o; o >>= 1) {
            double ov = __shfl_xor(bv, o); int oi = __shfl_xor(bi, o);
            if (ov > bv || (ov == bv && oi < bi)) { bv = ov; bi = oi; }
        }
        if (lane == 0) { rv[wid] = bv; ri[wid] = bi; }
        __syncthreads();
        if (t == 0) {
            for (int wv = 1; wv < 4; ++wv)
                if (rv[wv] > bv || (rv[wv] == bv && ri[wv] < bi)) { bv = rv[wv]; bi = ri[wv]; }
            if (side == 0) { bestSd[r] = bv; bestI[r] = bi; }
            else           { bestPSd[r] = bv; bestPI[r] = bi; }
        }
    }
}

// ---------------- K4: image sim/softmax + select output + seeding ----------------
__global__ void k_im_select(const float* __restrict__ imn,
                            const double* __restrict__ bestSd,
                            const int* __restrict__ bestI,
                            float* __restrict__ outSelect,
                            int* __restrict__ seed) {
    int p = blockIdx.x * 4 + (threadIdx.x >> 6);
    int lane = threadIdx.x & 63;
    int h = p >> 7;
    int w = p & 127;
    float2 ctr = *(const float2*)&imn[p * CC + lane * 2];

    double sim[KK];
#pragma unroll
    for (int k = 0; k < KK; ++k) {
        int di = k / 5 - 2, dj = k % 5 - 2;
        int hc = min(max(h + di, 0), HH - 1);
        int wc = min(max(w + dj, 0), WW - 1);
        int q = hc * WW + wc;
        float2 nv = *(const float2*)&imn[q * CC + lane * 2];
        double part = (double)ctr.x * (double)nv.x + (double)ctr.y * (double)nv.y;
#pragma unroll
        for (int o = 32; o; o >>= 1) part += __shfl_xor(part, o);
        sim[k] = part;
    }
    double mx = sim[0];
#pragma unroll
    for (int k = 1; k < KK; ++k) mx = fmax(mx, sim[k]);
    double sum = 0.0;
#pragma unroll
    for (int k = 0; k < KK; ++k) { sim[k] = exp(sim[k] - mx); sum += sim[k]; }
    double inv = 1.0 / sum;

    double sel[KK];
#pragma unroll
    for (int k = 0; k < KK; ++k) {
        int di = k / 5 - 2, dj = k % 5 - 2;
        int h2 = h + di, w2 = w + dj;
        bool valid = (h2 >= 0 && h2 < HH && w2 >= 0 && w2 < WW);
        int hc = min(max(h2, 0), HH - 1), wc = min(max(w2, 0), WW - 1);
        double conf = bestSd[hc * WW + wc];
        double so = valid ? (sim[k] * inv * conf) : (double)NEGV;
        if (lane == k) outSelect[k * PP + p] = (float)so;
        sel[k] = (k == 12) ? (double)NEGV : so;
    }

    int tk1 = 0, tk2 = 0, tk3 = 0, tk4 = 0;
    {
        unsigned chosen = 1u << 12;
#pragma unroll
        for (int s = 0; s < 4; ++s) {
            double bvv = -1e300; int bk = 0;
#pragma unroll
            for (int k = 0; k < KK; ++k)
                if (!((chosen >> k) & 1) && sel[k] > bvv) { bvv = sel[k]; bk = k; }
            chosen |= 1u << bk;
            if (s == 0) tk1 = bk; else if (s == 1) tk2 = bk; else if (s == 2) tk3 = bk; else tk4 = bk;
        }
    }
    if (lane == 0) {
        int tks[5] = {12, tk1, tk2, tk3, tk4};
#pragma unroll
        for (int s = 0; s < 5; ++s) {
            int k = tks[s];
            int di = k / 5 - 2, dj = k % 5 - 2;
            int h2 = h + di, w2 = w + dj;
            int pix = (h2 >= 0 && h2 < HH && w2 >= 0 && w2 < WW) ? (h2 * WW + w2) : -1;
            pix = min(max(pix, 0), PP - 1);
            seed[p * SPOT + s] = bestI[pix];
        }
    }
}

// ---------------- K6: pc sim/softmax + seeding -----------------------------------
__global__ void k_pc_select(const float* __restrict__ pcn,
                            const int* __restrict__ nb,
                            const double* __restrict__ bestPSd,
                            const int* __restrict__ bestPI,
                            int* __restrict__ pcseed) {
    int i = blockIdx.x * 4 + (threadIdx.x >> 6);
    int lane = threadIdx.x & 63;
    float2 ctr = *(const float2*)&pcn[i * CC + lane * 2];

    int nbr[KK];
#pragma unroll
    for (int k = 0; k < KK; ++k) nbr[k] = nb[i * KK + k];

    double sim[KK];
#pragma unroll
    for (int k = 0; k < KK; ++k) {
        float2 nv = *(const float2*)&pcn[nbr[k] * CC + lane * 2];
        double part = (double)ctr.x * (double)nv.x + (double)ctr.y * (double)nv.y;
#pragma unroll
        for (int o = 32; o; o >>= 1) part += __shfl_xor(part, o);
        sim[k] = part;
    }
    double mx = sim[0];
#pragma unroll
    for (int k = 1; k < KK; ++k) mx = fmax(mx, sim[k]);
    double sum = 0.0;
#pragma unroll
    for (int k = 0; k < KK; ++k) { sim[k] = exp(sim[k] - mx); sum += sim[k]; }
    double inv = 1.0 / sum;

    double sel[KK];
    sel[0] = (double)NEGV;
#pragma unroll
    for (int k = 1; k < KK; ++k) sel[k] = sim[k] * inv * bestPSd[nbr[k]];

    int tk1 = 0, tk2 = 0, tk3 = 0, tk4 = 0;
    {
        unsigned chosen = 0u;
#pragma unroll
        for (int s = 0; s < 4; ++s) {
            double bvv = -1e300; int bk = 0;
#pragma unroll
            for (int k = 0; k < KK; ++k)
                if (!((chosen >> k) & 1) && sel[k] > bvv) { bvv = sel[k]; bk = k; }
            chosen |= 1u << bk;
            if (s == 0) tk1 = bk; else if (s == 1) tk2 = bk; else if (s == 2) tk3 = bk; else tk4 = bk;
        }
    }
    if (lane == 0) {
        int tks[5] = {0, tk1, tk2, tk3, tk4};
#pragma unroll
        for (int s = 0; s < 5; ++s)
            pcseed[i * SPOT + s] = bestPI[nbr[tks[s]]];
    }
}

// ---------------- bitmap -> stable top-125 compaction ----------------------------
__device__ __forceinline__ void compact_bits(const unsigned* bits, int row,
                                             float* __restrict__ maskOut,
                                             float* __restrict__ idxOut, int lane) {
    int base = 0;
    for (int w = 0; w < 160 && base < 125; ++w) {
        unsigned word = bits[w];
        int cnt = __popc(word);
        if (lane < cnt) {
            unsigned v = word;
            for (int t = 0; t < lane; ++t) v &= v - 1;
            int pos = __ffs((int)v) - 1;
            idxOut[row * 125 + base + lane]  = (float)(w * 32 + pos);
            maskOut[row * 125 + base + lane] = 1.0f;
        }
        base += cnt;
    }
    for (int w = 0; w < 160 && base < 125; ++w) {
        unsigned word = ~bits[w];
        int cnt = __popc(word);
        int take = min(cnt, 125 - base);
        if (lane < take) {
            unsigned v = word;
            for (int t = 0; t < lane; ++t) v &= v - 1;
            int pos = __ffs((int)v) - 1;
            idxOut[row * 125 + base + lane]  = (float)(w * 32 + pos);
            maskOut[row * 125 + base + lane] = 0.0f;
        }
        base += take;
    }
}

// ---------------- K5: im spoting ------------------------------------------------
__global__ void k_im_spot(const int* __restrict__ seed, const int* __restrict__ nb,
                          float* __restrict__ maskOut, float* __restrict__ idxOut) {
    __shared__ unsigned bits[4][160];
    int wid = threadIdx.x >> 6, lane = threadIdx.x & 63;
    int p = blockIdx.x * 4 + wid;
    for (int w = lane; w < 160; w += 64) bits[wid][w] = 0u;
    __syncthreads();
    for (int e = lane; e < 125; e += 64) {
        int sd = seed[p * SPOT + e / 25];
        int pt = nb[sd * KK + (e % 25)];
        atomicOr(&bits[wid][pt >> 5], 1u << (pt & 31));
    }
    __syncthreads();
    compact_bits(bits[wid], p, maskOut, idxOut, lane);
}

// ---------------- K7: pc spoting ------------------------------------------------
__global__ void k_pc_spot(const int* __restrict__ pcseed,
                          float* __restrict__ maskOut, float* __restrict__ idxOut) {
    __shared__ unsigned bits[4][160];
    int wid = threadIdx.x >> 6, lane = threadIdx.x & 63;
    int i = blockIdx.x * 4 + wid;
    for (int w = lane; w < 160; w += 64) bits[wid][w] = 0u;
    __syncthreads();
    for (int e = lane; e < 125; e += 64) {
        int q = pcseed[i * SPOT + e / 25];
        int kk = e % 25;
        int r0 = q >> 7, c0 = q & 127;
        int r = min(max(r0 + kk / 5 - 2, 0), HH - 1);
        int c = min(max(c0 + kk % 5 - 2, 0), WW - 1);
        int pix = r * WW + c;
        atomicOr(&bits[wid][pix >> 5], 1u << (pix & 31));
    }
    __syncthreads();
    compact_bits(bits[wid], i, maskOut, idxOut, lane);
}

// ---------------- host ----------------------------------------------------------
extern "C" void kernel_launch(void* const* d_in, const int* in_sizes, int n_in,
                              void* d_out, int out_size, void* d_ws, size_t ws_size,
                              hipStream_t stream) {
    const float* imf = (const float*)d_in[0];
    const float* pcf = (const float*)d_in[1];
    const float* pts = (const float*)d_in[2];
    float* out = (float*)d_out;

    char* w = (char*)d_ws;
    double* bestSd  = (double*)w;  w += (size_t)PP * 8;
    double* bestPSd = (double*)w;  w += (size_t)NN * 8;
    float*  imn     = (float*)w;   w += (size_t)PP * CC * 4;
    float*  pcn     = (float*)w;   w += (size_t)NN * CC * 4;
    float*  pval    = (float*)w;   w += (size_t)2 * CSPLIT * PP * 4;
    float*  pv2     = (float*)w;   w += (size_t)2 * CSPLIT * PP * 4;
    int*    pidx    = (int*)w;     w += (size_t)2 * CSPLIT * PP * 4;
    int*    nb      = (int*)w;     w += (size_t)NN * KK * 4;
    int*    bestI   = (int*)w;     w += (size_t)PP * 4;
    int*    bestPI  = (int*)w;     w += (size_t)NN * 4;
    int*    seed    = (int*)w;     w += (size_t)PP * SPOT * 4;
    int*    pcseed  = (int*)w;     w += (size_t)NN * SPOT * 4;
    int*    list    = (int*)w;     w += (size_t)(PP + NN) * 4;
    int*    cnt     = (int*)w;     w += 256;

    float* outSelect = out;                       // (25, 5120)
    float* outMask   = out + KK * PP;             // (5120, 125)
    float* outIdx    = outMask + PP * 125;        // (5120, 125)
    float* outIdxPc  = outIdx + PP * 125;         // (5120, 125)
    float* outMaskPc = outIdxPc + NN * 125;       // (5120, 125)

    hipMemsetAsync(cnt, 0, 4, stream);
    k_normalize<<<(PP + NN) / 4, 256, 0, stream>>>(imf, pcf, imn, pcn);
    k_knn<<<NN, 256, 0, stream>>>(pts, nb);
    k_rowmax<<<dim3(PP / TM, CSPLIT, 2), 256, 0, stream>>>(imn, pcn, pval, pv2, pidx);
    k_reduce_best<<<dim3(PP / 256, 2), 256, 0, stream>>>(pval, pv2, pidx,
                                                         bestSd, bestI, bestPSd, bestPI,
                                                         list, cnt);
    k_recheck<<<64, 256, 0, stream>>>(imn, pcn, list, cnt, bestSd, bestI, bestPSd, bestPI);
    k_im_select<<<PP / 4, 256, 0, stream>>>(imn, bestSd, bestI, outSelect, seed);
    k_pc_select<<<NN / 4, 256, 0, stream>>>(pcn, nb, bestPSd, bestPI, pcseed);
    k_im_spot<<<PP / 4, 256, 0, stream>>>(seed, nb, outMask, outIdx);
    k_pc_spot<<<NN / 4, 256, 0, stream>>>(pcseed, outMaskPc, outIdxPc);
}